// Round 1
// baseline (227.208 us; speedup 1.0000x reference)
//
#include <hip/hip_runtime.h>
#include <math.h>

#define DFEAT   128
#define KSPLIT  16      // blocks per segment in pass 1
#define GROUPS  8       // 256 threads / 32-lane groups
#define NEG_INF (-INFINITY)

// ---------------------------------------------------------------------------
// Kernel 0: segment boundaries via binary search (batch_index is sorted).
// seg_starts[t] = first index v with batch_index[v] >= t, for t in [0, B].
// ---------------------------------------------------------------------------
__global__ void seg_bounds_kernel(const int* __restrict__ bidx, int V, int B,
                                  int* __restrict__ seg_starts) {
    int t = threadIdx.x;
    if (t > B) return;
    int lo = 0, hi = V;
    while (lo < hi) {
        int mid = (lo + hi) >> 1;
        if (bidx[mid] < t) lo = mid + 1; else hi = mid;
    }
    seg_starts[t] = lo;
}

// ---------------------------------------------------------------------------
// Kernel 1: one streaming pass over node_feats with online softmax.
// Block (b, j) handles slice j of segment b. Each 32-lane group keeps a
// private (m, Z, num[4/lane]) state; groups merged via LDS at the end.
// Writes one partial (M, Z, NUM[128]) per block.
// ---------------------------------------------------------------------------
__global__ __launch_bounds__(256) void pass1_kernel(
    const float* __restrict__ node_feats,
    const float* __restrict__ Q,
    const int*   __restrict__ seg_starts,
    float* __restrict__ M, float* __restrict__ Zp, float* __restrict__ NUM)
{
    const int blk  = blockIdx.x;
    const int b    = blk / KSPLIT;
    const int j    = blk % KSPLIT;
    const int tid  = threadIdx.x;
    const int g    = tid >> 5;   // group id 0..7 (uniform within 32 lanes)
    const int lane = tid & 31;   // lane within group

    const int start = seg_starts[b];
    const int end   = seg_starts[b + 1];
    const int len   = end - start;
    const int my_s  = start + (int)(((long long)len * j)       / KSPLIT);
    const int my_e  = start + (int)(((long long)len * (j + 1)) / KSPLIT);

    const float4* nf4 = (const float4*)node_feats;
    const float4  q   = ((const float4*)(Q + (size_t)b * DFEAT))[lane];

    float  m = NEG_INF, Z = 0.f;
    float4 num = {0.f, 0.f, 0.f, 0.f};

    for (int v = my_s + g; v < my_e; v += GROUPS) {
        const float4 x = nf4[(size_t)v * (DFEAT / 4) + lane];
        float s = x.x * q.x + x.y * q.y + x.z * q.z + x.w * q.w;
        // reduce dot product across the 32-lane group (stays within group)
        s += __shfl_xor(s, 1);
        s += __shfl_xor(s, 2);
        s += __shfl_xor(s, 4);
        s += __shfl_xor(s, 8);
        s += __shfl_xor(s, 16);
        s *= 0.08838834764831845f;  // 1/sqrt(128)
        if (s > m) {                 // group-uniform branch
            const float f = __expf(m - s);   // exp(-inf)=0 on first node
            Z *= f;
            num.x *= f; num.y *= f; num.z *= f; num.w *= f;
            m = s;
        }
        const float e = __expf(s - m);
        Z += e;
        num.x += e * x.x; num.y += e * x.y; num.z += e * x.z; num.w += e * x.w;
    }

    // ---- merge 8 group-partials into one block-partial via LDS ----
    __shared__ float gm[GROUPS], gz[GROUPS];
    __shared__ float nm[GROUPS][DFEAT];
    if (lane == 0) { gm[g] = m; gz[g] = Z; }
    __syncthreads();

    float mstar = gm[0];
    #pragma unroll
    for (int i = 1; i < GROUPS; ++i) mstar = fmaxf(mstar, gm[i]);

    const float f = (m == NEG_INF) ? 0.f : __expf(m - mstar);
    nm[g][4 * lane + 0] = num.x * f;
    nm[g][4 * lane + 1] = num.y * f;
    nm[g][4 * lane + 2] = num.z * f;
    nm[g][4 * lane + 3] = num.w * f;
    __syncthreads();

    if (tid < DFEAT) {
        float acc = 0.f;
        #pragma unroll
        for (int i = 0; i < GROUPS; ++i) acc += nm[i][tid];
        NUM[(size_t)blk * DFEAT + tid] = acc;
    }
    if (tid == 0) {
        float Zb = 0.f;
        #pragma unroll
        for (int i = 0; i < GROUPS; ++i) {
            const float fi = (gm[i] == NEG_INF) ? 0.f : __expf(gm[i] - mstar);
            Zb += gz[i] * fi;
        }
        M[blk]  = mstar;   // -inf if slice empty
        Zp[blk] = Zb;
    }
}

// ---------------------------------------------------------------------------
// Kernel 2: merge the KSPLIT partials of each segment and write H[b][:].
// ---------------------------------------------------------------------------
__global__ __launch_bounds__(128) void pass2_kernel(
    const float* __restrict__ M, const float* __restrict__ Zp,
    const float* __restrict__ NUM, float* __restrict__ H)
{
    const int b = blockIdx.x;
    const int d = threadIdx.x;

    float mstar = NEG_INF;
    #pragma unroll
    for (int i = 0; i < KSPLIT; ++i) mstar = fmaxf(mstar, M[b * KSPLIT + i]);

    if (mstar == NEG_INF) {          // empty segment -> zero row
        H[(size_t)b * DFEAT + d] = 0.f;
        return;
    }

    float W = 0.f, acc = 0.f;
    #pragma unroll
    for (int i = 0; i < KSPLIT; ++i) {
        const float mi = M[b * KSPLIT + i];
        const float fi = (mi == NEG_INF) ? 0.f : __expf(mi - mstar);
        W   += Zp[b * KSPLIT + i] * fi;
        acc += NUM[(size_t)(b * KSPLIT + i) * DFEAT + d] * fi;
    }
    H[(size_t)b * DFEAT + d] = acc / W;   // W >= 1 when segment nonempty
}

// ---------------------------------------------------------------------------
extern "C" void kernel_launch(void* const* d_in, const int* in_sizes, int n_in,
                              void* d_out, int out_size, void* d_ws, size_t ws_size,
                              hipStream_t stream) {
    const float* node_feats = (const float*)d_in[0];  // [V, 128]
    const float* Q          = (const float*)d_in[1];  // [B, 128]
    const int*   bidx       = (const int*)  d_in[2];  // [V] sorted
    float*       H          = (float*)d_out;          // [V, 128]

    const int V = in_sizes[2];
    const int B = in_sizes[1] / DFEAT;

    // workspace layout (512B-aligned chunks)
    char* ws = (char*)d_ws;
    size_t off = 0;
    int* seg_starts = (int*)(ws + off);
    off += ((size_t)(B + 1) * sizeof(int) + 511) & ~(size_t)511;
    float* M  = (float*)(ws + off);
    off += ((size_t)B * KSPLIT * sizeof(float) + 511) & ~(size_t)511;
    float* Zp = (float*)(ws + off);
    off += ((size_t)B * KSPLIT * sizeof(float) + 511) & ~(size_t)511;
    float* NUM = (float*)(ws + off);

    // rows >= B are zero in the reference; d_out is poisoned once before
    // timing, so produce zeros every call.
    hipMemsetAsync(d_out, 0, (size_t)out_size * sizeof(float), stream);

    seg_bounds_kernel<<<1, 512, 0, stream>>>(bidx, V, B, seg_starts);
    pass1_kernel<<<B * KSPLIT, 256, 0, stream>>>(node_feats, Q, seg_starts, M, Zp, NUM);
    pass2_kernel<<<B, DFEAT, 0, stream>>>(M, Zp, NUM, H);
}